// Round 1
// baseline (9071.564 us; speedup 1.0000x reference)
//
#include <hip/hip_runtime.h>
#include <hip/hip_bf16.h>

#define VOCAB 50000
#define DD 256
#define NCLS 10
#define BB 64
#define SS 512
#define HH 512

// ---------------------------------------------------------------------------
// Kernel 1: pre-GEMM with fused embedding gather.
// pre_l[s,b,n] = sum_d embed_w[x[b,s],d]*Wsl[n,d] + bsl[n]   (same for r)
// grid = S * (D/64) = 2048 blocks, 256 threads.
// Block handles one s (64 b-rows) x 64 n-cols for BOTH Wsl and Wsr.
// ---------------------------------------------------------------------------
__global__ __launch_bounds__(256) void pre_gemm_kernel(
    const int* __restrict__ x, const float* __restrict__ embed_w,
    const float* __restrict__ Wsl, const float* __restrict__ bsl,
    const float* __restrict__ Wsr, const float* __restrict__ bsr,
    float* __restrict__ pre_l, float* __restrict__ pre_r)
{
    __shared__ float As[64][65];   // [b][k]
    __shared__ float Bl[64][65];   // [n][k]
    __shared__ float Br[64][65];
    __shared__ int   xs[64];

    const int s  = blockIdx.x >> 2;
    const int n0 = (blockIdx.x & 3) * 64;
    const int tid = threadIdx.x;
    const int bi = tid >> 4;   // b-group: b = bi*4 + r
    const int ni = tid & 15;   // n = n0 + ni + 16*j

    if (tid < 64) xs[tid] = x[tid * SS + s];

    float accl[4][4], accr[4][4];
#pragma unroll
    for (int r = 0; r < 4; ++r)
#pragma unroll
        for (int j = 0; j < 4; ++j) { accl[r][j] = 0.f; accr[r][j] = 0.f; }

    __syncthreads();

    for (int k0 = 0; k0 < DD; k0 += 64) {
#pragma unroll
        for (int j = 0; j < 16; ++j) {
            const int lin = tid + 256 * j;
            const int row = lin >> 6, col = lin & 63;
            As[row][col] = embed_w[(size_t)xs[row] * DD + k0 + col];
            Bl[row][col] = Wsl[(size_t)(n0 + row) * DD + k0 + col];
            Br[row][col] = Wsr[(size_t)(n0 + row) * DD + k0 + col];
        }
        __syncthreads();
#pragma unroll 8
        for (int k = 0; k < 64; ++k) {
            float a[4];
#pragma unroll
            for (int r = 0; r < 4; ++r) a[r] = As[bi * 4 + r][k];
#pragma unroll
            for (int j = 0; j < 4; ++j) {
                const float bvl = Bl[ni + 16 * j][k];
                const float bvr = Br[ni + 16 * j][k];
#pragma unroll
                for (int r = 0; r < 4; ++r) {
                    accl[r][j] += a[r] * bvl;
                    accr[r][j] += a[r] * bvr;
                }
            }
        }
        __syncthreads();
    }

#pragma unroll
    for (int r = 0; r < 4; ++r) {
        const int b = bi * 4 + r;
#pragma unroll
        for (int j = 0; j < 4; ++j) {
            const int n = n0 + ni + 16 * j;
            const size_t idx = ((size_t)s * BB + b) * DD + n;
            pre_l[idx] = accl[r][j] + bsl[n];
            pre_r[idx] = accr[r][j] + bsr[n];
        }
    }
}

// ---------------------------------------------------------------------------
// Kernel 2: the two recurrences. 128 blocks (dir*64 + b), 1024 threads.
// Weights resident in registers (64 f32/thread), state c in LDS,
// shuffle-reduce across 4-lane quads, double-buffered pre prefetch.
// left[t] = relu(Wl@left[t-1] + bl + pre_l[t-1]), left[0]=cl0
// right[t]= relu(Wr@right[t+1] + br + pre_r[t+1]), right[S-1]=cr0
// ---------------------------------------------------------------------------
__global__ __launch_bounds__(1024) void recur_kernel(
    const float* __restrict__ Wl, const float* __restrict__ bl,
    const float* __restrict__ Wr, const float* __restrict__ br,
    const float* __restrict__ cl0, const float* __restrict__ cr0,
    const float* __restrict__ pre_l, const float* __restrict__ pre_r,
    float* __restrict__ outl, float* __restrict__ outr)
{
    __shared__ alignas(16) float cbuf[2][256];
    __shared__ float pbuf[2][256];

    const int bid = blockIdx.x;
    const int dir = bid >> 6;
    const int b   = bid & 63;
    const float* W    = dir ? Wr  : Wl;
    const float* bias = dir ? br  : bl;
    const float* c0   = dir ? cr0 : cl0;
    const float* pre  = dir ? pre_r : pre_l;
    float* out        = dir ? outr : outl;

    const int tid = threadIdx.x;
    const int e = tid >> 2;    // output feature 0..255
    const int q = tid & 3;     // k-chunk 0..3 (d in [64q, 64q+64))

    // weights: wreg[i] = W[e][64q + 4i .. +3]
    float4 wreg[16];
    {
        const float4* wrow = (const float4*)(W + (size_t)e * DD + q * 64);
#pragma unroll
        for (int i = 0; i < 16; ++i) wreg[i] = wrow[i];
    }
    const float blv = bias[e];

    if (tid < 256) {
        cbuf[0][tid] = c0[b * DD + tid];
        const int t0 = dir ? 511 : 0;
        pbuf[0][tid] = pre[((size_t)t0 * BB + b) * DD + tid];
    }
    float preg = 0.f;
    if (tid < 256) {
        const int t1 = dir ? 510 : 1;
        preg = pre[((size_t)t1 * BB + b) * DD + tid];
    }
    __syncthreads();

    int cur = 0;
    for (int k = 0; k < SS; ++k) {
        const int t = dir ? (SS - 1 - k) : k;

        // prefetch pre for phys step k+2
        float pnext = 0.f;
        if (tid < 256 && (k + 2) < SS) {
            const int t2 = dir ? (SS - 1 - (k + 2)) : (k + 2);
            pnext = pre[((size_t)t2 * BB + b) * DD + tid];
        }
        // emit out[b][t][:] = c
        if (tid < 256) out[((size_t)b * SS + t) * DD + tid] = cbuf[cur][tid];

        if (k < SS - 1) {
            float partial = 0.f;
            const float4* c4 = (const float4*)cbuf[cur];
#pragma unroll
            for (int ii = 0; ii < 16; ++ii) {
                const int jj = (ii + 2 * q) & 15;      // bank-phase swizzle
                const float4 cv = c4[16 * q + jj];
                const float4 wv = wreg[jj];
                partial += wv.x * cv.x + wv.y * cv.y + wv.z * cv.z + wv.w * cv.w;
            }
            partial += __shfl_xor(partial, 1);
            partial += __shfl_xor(partial, 2);
            float v = partial + blv + pbuf[cur][e];
            v = v > 0.f ? v : 0.f;
            if (q == 0) cbuf[cur ^ 1][e] = v;
        }
        if (tid < 256 && (k + 1) < SS) pbuf[cur ^ 1][tid] = preg;
        preg = pnext;
        cur ^= 1;
        __syncthreads();
    }
}

// ---------------------------------------------------------------------------
// Kernel 3: conv(1x3D) + relu + maxpool over s, fused. Never materializes h.
// grid = B * (H/128) = 256 blocks, 256 threads.
// pooled[b,h] = max_s relu( sum_d ctx[b,s,d]*conv_w[h,d] + conv_b[h] )
// ctx = [left | gather(embed) | right]
// ---------------------------------------------------------------------------
__global__ __launch_bounds__(256) void conv_pool_kernel(
    const int* __restrict__ x, const float* __restrict__ embed_w,
    const float* __restrict__ left, const float* __restrict__ right,
    const float* __restrict__ conv_w, const float* __restrict__ conv_b,
    float* __restrict__ pooled)
{
    __shared__ float As[64][65];    // [s][k]
    __shared__ float Bs[128][65];   // [h][k]
    __shared__ float red[16][128];

    const int b  = blockIdx.x >> 2;
    const int h0 = (blockIdx.x & 3) * 128;
    const int tid = threadIdx.x;
    const int si = tid >> 4;   // s-group: s = s0 + si*4 + r
    const int hi = tid & 15;   // h = h0 + hi + 16*j

    float pmax[8];
#pragma unroll
    for (int j = 0; j < 8; ++j) pmax[j] = 0.f;   // relu >= 0

    for (int s0 = 0; s0 < SS; s0 += 64) {
        float acc[4][8];
#pragma unroll
        for (int r = 0; r < 4; ++r)
#pragma unroll
            for (int j = 0; j < 8; ++j) acc[r][j] = 0.f;

        for (int k0 = 0; k0 < 3 * DD; k0 += 64) {
            // stage A (ctx slice)
#pragma unroll
            for (int j = 0; j < 16; ++j) {
                const int lin = tid + 256 * j;
                const int row = lin >> 6, col = lin & 63;
                const int ss = s0 + row;
                float v;
                if (k0 < DD)
                    v = left[((size_t)b * SS + ss) * DD + k0 + col];
                else if (k0 < 2 * DD)
                    v = embed_w[(size_t)x[b * SS + ss] * DD + (k0 - DD) + col];
                else
                    v = right[((size_t)b * SS + ss) * DD + (k0 - 2 * DD) + col];
                As[row][col] = v;
            }
            // stage B (conv_w slice)
#pragma unroll
            for (int j = 0; j < 32; ++j) {
                const int lin = tid + 256 * j;
                const int row = lin >> 6, col = lin & 63;
                Bs[row][col] = conv_w[(size_t)(h0 + row) * (3 * DD) + k0 + col];
            }
            __syncthreads();
#pragma unroll 4
            for (int k = 0; k < 64; ++k) {
                float a[4];
#pragma unroll
                for (int r = 0; r < 4; ++r) a[r] = As[si * 4 + r][k];
#pragma unroll
                for (int j = 0; j < 8; ++j) {
                    const float bv = Bs[hi + 16 * j][k];
#pragma unroll
                    for (int r = 0; r < 4; ++r) acc[r][j] += a[r] * bv;
                }
            }
            __syncthreads();
        }
        // finalize this s-tile: bias, relu, running max
#pragma unroll
        for (int j = 0; j < 8; ++j) {
            const float cb = conv_b[h0 + hi + 16 * j];
#pragma unroll
            for (int r = 0; r < 4; ++r) {
                float v = acc[r][j] + cb;
                v = v > 0.f ? v : 0.f;
                pmax[j] = pmax[j] > v ? pmax[j] : v;
            }
        }
    }
    // reduce pmax across the 16 si-groups
#pragma unroll
    for (int j = 0; j < 8; ++j) red[si][hi + 16 * j] = pmax[j];
    __syncthreads();
    if (tid < 128) {
        float m = red[0][tid];
#pragma unroll
        for (int g = 1; g < 16; ++g) m = m > red[g][tid] ? m : red[g][tid];
        pooled[(size_t)b * HH + h0 + tid] = m;
    }
}

// ---------------------------------------------------------------------------
// Kernel 4: final FC. out[b,c] = pooled[b,:] @ fc_w[c,:] + fc_b[c]
// ---------------------------------------------------------------------------
__global__ void fc_kernel(const float* __restrict__ pooled,
                          const float* __restrict__ fc_w,
                          const float* __restrict__ fc_b,
                          float* __restrict__ out)
{
    const int t = threadIdx.x;
    if (t >= BB * NCLS) return;
    const int b = t / NCLS, c = t % NCLS;
    float acc = fc_b[c];
    for (int h = 0; h < HH; ++h)
        acc += pooled[(size_t)b * HH + h] * fc_w[(size_t)c * HH + h];
    out[b * NCLS + c] = acc;
}

// ---------------------------------------------------------------------------
extern "C" void kernel_launch(void* const* d_in, const int* in_sizes, int n_in,
                              void* d_out, int out_size, void* d_ws, size_t ws_size,
                              hipStream_t stream)
{
    const int*   x       = (const int*)  d_in[0];
    const float* embed_w = (const float*)d_in[1];
    const float* Wl      = (const float*)d_in[2];
    const float* bl      = (const float*)d_in[3];
    const float* Wsl     = (const float*)d_in[4];
    const float* bsl     = (const float*)d_in[5];
    const float* Wr      = (const float*)d_in[6];
    const float* br      = (const float*)d_in[7];
    const float* Wsr     = (const float*)d_in[8];
    const float* bsr     = (const float*)d_in[9];
    const float* conv_w  = (const float*)d_in[10];
    const float* conv_b  = (const float*)d_in[11];
    const float* fc_w    = (const float*)d_in[12];
    const float* fc_b    = (const float*)d_in[13];
    const float* cl0     = (const float*)d_in[14];
    const float* cr0     = (const float*)d_in[15];
    float* out = (float*)d_out;

    char* ws = (char*)d_ws;
    const size_t SZ = (size_t)SS * BB * DD * sizeof(float);  // 33.55 MB
    float* pre_l  = (float*)(ws);
    float* pre_r  = (float*)(ws + SZ);
    float* leftb  = (float*)(ws + 2 * SZ);
    float* rightb = (float*)(ws + 3 * SZ);
    float* pooled = (float*)(ws + 4 * SZ);

    pre_gemm_kernel<<<SS * (DD / 64), 256, 0, stream>>>(
        x, embed_w, Wsl, bsl, Wsr, bsr, pre_l, pre_r);

    recur_kernel<<<128, 1024, 0, stream>>>(
        Wl, bl, Wr, br, cl0, cr0, pre_l, pre_r, leftb, rightb);

    conv_pool_kernel<<<BB * (HH / 128), 256, 0, stream>>>(
        x, embed_w, leftb, rightb, conv_w, conv_b, pooled);

    fc_kernel<<<1, BB * NCLS, 0, stream>>>(pooled, fc_w, fc_b, out);
}

// Round 2
// 1764.619 us; speedup vs baseline: 5.1408x; 5.1408x over previous
//
#include <hip/hip_runtime.h>
#include <hip/hip_bf16.h>

#define VOCAB 50000
#define DD 256
#define NCLS 10
#define BB 64
#define SS 512
#define HH 512

// ---------------------------------------------------------------------------
// Kernel 1: pre-GEMM with fused embedding gather.
// pre_l[s,b,n] = sum_d embed_w[x[b,s],d]*Wsl[n,d] + bsl[n]   (same for r)
// grid = S * (D/64) = 2048 blocks, 256 threads.
// Block handles one s (64 b-rows) x 64 n-cols for BOTH Wsl and Wsr.
// ---------------------------------------------------------------------------
__global__ __launch_bounds__(256) void pre_gemm_kernel(
    const int* __restrict__ x, const float* __restrict__ embed_w,
    const float* __restrict__ Wsl, const float* __restrict__ bsl,
    const float* __restrict__ Wsr, const float* __restrict__ bsr,
    float* __restrict__ pre_l, float* __restrict__ pre_r)
{
    __shared__ float As[64][65];   // [b][k]
    __shared__ float Bl[64][65];   // [n][k]
    __shared__ float Br[64][65];
    __shared__ int   xs[64];

    const int s  = blockIdx.x >> 2;
    const int n0 = (blockIdx.x & 3) * 64;
    const int tid = threadIdx.x;
    const int bi = tid >> 4;   // b-group: b = bi*4 + r
    const int ni = tid & 15;   // n = n0 + ni + 16*j

    if (tid < 64) xs[tid] = x[tid * SS + s];

    float accl[4][4], accr[4][4];
#pragma unroll
    for (int r = 0; r < 4; ++r)
#pragma unroll
        for (int j = 0; j < 4; ++j) { accl[r][j] = 0.f; accr[r][j] = 0.f; }

    __syncthreads();

    for (int k0 = 0; k0 < DD; k0 += 64) {
#pragma unroll
        for (int j = 0; j < 16; ++j) {
            const int lin = tid + 256 * j;
            const int row = lin >> 6, col = lin & 63;
            As[row][col] = embed_w[(size_t)xs[row] * DD + k0 + col];
            Bl[row][col] = Wsl[(size_t)(n0 + row) * DD + k0 + col];
            Br[row][col] = Wsr[(size_t)(n0 + row) * DD + k0 + col];
        }
        __syncthreads();
#pragma unroll 8
        for (int k = 0; k < 64; ++k) {
            float a[4];
#pragma unroll
            for (int r = 0; r < 4; ++r) a[r] = As[bi * 4 + r][k];
#pragma unroll
            for (int j = 0; j < 4; ++j) {
                const float bvl = Bl[ni + 16 * j][k];
                const float bvr = Br[ni + 16 * j][k];
#pragma unroll
                for (int r = 0; r < 4; ++r) {
                    accl[r][j] += a[r] * bvl;
                    accr[r][j] += a[r] * bvr;
                }
            }
        }
        __syncthreads();
    }

#pragma unroll
    for (int r = 0; r < 4; ++r) {
        const int b = bi * 4 + r;
#pragma unroll
        for (int j = 0; j < 4; ++j) {
            const int n = n0 + ni + 16 * j;
            const size_t idx = ((size_t)s * BB + b) * DD + n;
            pre_l[idx] = accl[r][j] + bsl[n];
            pre_r[idx] = accr[r][j] + bsr[n];
        }
    }
}

// ---------------------------------------------------------------------------
// Kernel 2: the two recurrences. 128 blocks (dir*64 + b), 1024 threads.
// Weights resident in registers (64 f32/thread, STATICALLY indexed — the
// bank-phase rotation is applied at load time and on the LDS address, never
// on the register array index; runtime register indexing spills to scratch).
// State c in LDS, shuffle-reduce across 4-lane quads, double-buffered pre.
// left[t] = relu(Wl@left[t-1] + bl + pre_l[t-1]), left[0]=cl0
// right[t]= relu(Wr@right[t+1] + br + pre_r[t+1]), right[S-1]=cr0
// ---------------------------------------------------------------------------
__global__ __launch_bounds__(1024) void recur_kernel(
    const float* __restrict__ Wl, const float* __restrict__ bl,
    const float* __restrict__ Wr, const float* __restrict__ br,
    const float* __restrict__ cl0, const float* __restrict__ cr0,
    const float* __restrict__ pre_l, const float* __restrict__ pre_r,
    float* __restrict__ outl, float* __restrict__ outr)
{
    __shared__ alignas(16) float cbuf[2][256];
    __shared__ float pbuf[2][256];

    const int bid = blockIdx.x;
    const int dir = bid >> 6;
    const int b   = bid & 63;
    const float* W    = dir ? Wr  : Wl;
    const float* bias = dir ? br  : bl;
    const float* c0   = dir ? cr0 : cl0;
    const float* pre  = dir ? pre_r : pre_l;
    float* out        = dir ? outr : outl;

    const int tid = threadIdx.x;
    const int e = tid >> 2;    // output feature 0..255
    const int q = tid & 3;     // k-chunk 0..3 (d in [64q, 64q+64))

    // weights, pre-rotated by the bank-phase swizzle so the in-loop register
    // index is STATIC: wreg[i] = W[e][64q + 4*((i+2q)&15) .. +3]
    float4 wreg[16];
    {
        const float4* wrow = (const float4*)(W + (size_t)e * DD + q * 64);
#pragma unroll
        for (int i = 0; i < 16; ++i) wreg[i] = wrow[(i + 2 * q) & 15];
    }
    const float blv = bias[e];

    if (tid < 256) {
        cbuf[0][tid] = c0[b * DD + tid];
        const int t0 = dir ? 511 : 0;
        pbuf[0][tid] = pre[((size_t)t0 * BB + b) * DD + tid];
    }
    float preg = 0.f;
    if (tid < 256) {
        const int t1 = dir ? 510 : 1;
        preg = pre[((size_t)t1 * BB + b) * DD + tid];
    }
    __syncthreads();

    int cur = 0;
    for (int k = 0; k < SS; ++k) {
        const int t = dir ? (SS - 1 - k) : k;

        // prefetch pre for phys step k+2
        float pnext = 0.f;
        if (tid < 256 && (k + 2) < SS) {
            const int t2 = dir ? (SS - 1 - (k + 2)) : (k + 2);
            pnext = pre[((size_t)t2 * BB + b) * DD + tid];
        }
        // emit out[b][t][:] = c
        if (tid < 256) out[((size_t)b * SS + t) * DD + tid] = cbuf[cur][tid];

        if (k < SS - 1) {
            float partial = 0.f;
            const float4* c4 = (const float4*)cbuf[cur] + 16 * q;
#pragma unroll
            for (int ii = 0; ii < 16; ++ii) {
                const float4 cv = c4[(ii + 2 * q) & 15];  // runtime LDS addr: OK
                const float4 wv = wreg[ii];               // static reg index
                partial += wv.x * cv.x + wv.y * cv.y + wv.z * cv.z + wv.w * cv.w;
            }
            partial += __shfl_xor(partial, 1);
            partial += __shfl_xor(partial, 2);
            float v = partial + blv + pbuf[cur][e];
            v = v > 0.f ? v : 0.f;
            if (q == 0) cbuf[cur ^ 1][e] = v;
        }
        if (tid < 256 && (k + 1) < SS) pbuf[cur ^ 1][tid] = preg;
        preg = pnext;
        cur ^= 1;
        __syncthreads();
    }
}

// ---------------------------------------------------------------------------
// Kernel 3: conv(1x3D) + relu + maxpool over s, fused. Never materializes h.
// grid = B * (H/128) = 256 blocks, 256 threads.
// pooled[b,h] = max_s relu( sum_d ctx[b,s,d]*conv_w[h,d] + conv_b[h] )
// ctx = [left | gather(embed) | right]
// ---------------------------------------------------------------------------
__global__ __launch_bounds__(256) void conv_pool_kernel(
    const int* __restrict__ x, const float* __restrict__ embed_w,
    const float* __restrict__ left, const float* __restrict__ right,
    const float* __restrict__ conv_w, const float* __restrict__ conv_b,
    float* __restrict__ pooled)
{
    __shared__ float As[64][65];    // [s][k]
    __shared__ float Bs[128][65];   // [h][k]
    __shared__ float red[16][128];

    const int b  = blockIdx.x >> 2;
    const int h0 = (blockIdx.x & 3) * 128;
    const int tid = threadIdx.x;
    const int si = tid >> 4;   // s-group: s = s0 + si*4 + r
    const int hi = tid & 15;   // h = h0 + hi + 16*j

    float pmax[8];
#pragma unroll
    for (int j = 0; j < 8; ++j) pmax[j] = 0.f;   // relu >= 0

    for (int s0 = 0; s0 < SS; s0 += 64) {
        float acc[4][8];
#pragma unroll
        for (int r = 0; r < 4; ++r)
#pragma unroll
            for (int j = 0; j < 8; ++j) acc[r][j] = 0.f;

        for (int k0 = 0; k0 < 3 * DD; k0 += 64) {
            // stage A (ctx slice)
#pragma unroll
            for (int j = 0; j < 16; ++j) {
                const int lin = tid + 256 * j;
                const int row = lin >> 6, col = lin & 63;
                const int ss = s0 + row;
                float v;
                if (k0 < DD)
                    v = left[((size_t)b * SS + ss) * DD + k0 + col];
                else if (k0 < 2 * DD)
                    v = embed_w[(size_t)x[b * SS + ss] * DD + (k0 - DD) + col];
                else
                    v = right[((size_t)b * SS + ss) * DD + (k0 - 2 * DD) + col];
                As[row][col] = v;
            }
            // stage B (conv_w slice)
#pragma unroll
            for (int j = 0; j < 32; ++j) {
                const int lin = tid + 256 * j;
                const int row = lin >> 6, col = lin & 63;
                Bs[row][col] = conv_w[(size_t)(h0 + row) * (3 * DD) + k0 + col];
            }
            __syncthreads();
#pragma unroll 4
            for (int k = 0; k < 64; ++k) {
                float a[4];
#pragma unroll
                for (int r = 0; r < 4; ++r) a[r] = As[si * 4 + r][k];
#pragma unroll
                for (int j = 0; j < 8; ++j) {
                    const float bv = Bs[hi + 16 * j][k];
#pragma unroll
                    for (int r = 0; r < 4; ++r) acc[r][j] += a[r] * bv;
                }
            }
            __syncthreads();
        }
        // finalize this s-tile: bias, relu, running max
#pragma unroll
        for (int j = 0; j < 8; ++j) {
            const float cb = conv_b[h0 + hi + 16 * j];
#pragma unroll
            for (int r = 0; r < 4; ++r) {
                float v = acc[r][j] + cb;
                v = v > 0.f ? v : 0.f;
                pmax[j] = pmax[j] > v ? pmax[j] : v;
            }
        }
    }
    // reduce pmax across the 16 si-groups
#pragma unroll
    for (int j = 0; j < 8; ++j) red[si][hi + 16 * j] = pmax[j];
    __syncthreads();
    if (tid < 128) {
        float m = red[0][tid];
#pragma unroll
        for (int g = 1; g < 16; ++g) m = m > red[g][tid] ? m : red[g][tid];
        pooled[(size_t)b * HH + h0 + tid] = m;
    }
}

// ---------------------------------------------------------------------------
// Kernel 4: final FC. out[b,c] = pooled[b,:] @ fc_w[c,:] + fc_b[c]
// ---------------------------------------------------------------------------
__global__ void fc_kernel(const float* __restrict__ pooled,
                          const float* __restrict__ fc_w,
                          const float* __restrict__ fc_b,
                          float* __restrict__ out)
{
    const int t = threadIdx.x;
    if (t >= BB * NCLS) return;
    const int b = t / NCLS, c = t % NCLS;
    float acc = fc_b[c];
    for (int h = 0; h < HH; ++h)
        acc += pooled[(size_t)b * HH + h] * fc_w[(size_t)c * HH + h];
    out[b * NCLS + c] = acc;
}

// ---------------------------------------------------------------------------
extern "C" void kernel_launch(void* const* d_in, const int* in_sizes, int n_in,
                              void* d_out, int out_size, void* d_ws, size_t ws_size,
                              hipStream_t stream)
{
    const int*   x       = (const int*)  d_in[0];
    const float* embed_w = (const float*)d_in[1];
    const float* Wl      = (const float*)d_in[2];
    const float* bl      = (const float*)d_in[3];
    const float* Wsl     = (const float*)d_in[4];
    const float* bsl     = (const float*)d_in[5];
    const float* Wr      = (const float*)d_in[6];
    const float* br      = (const float*)d_in[7];
    const float* Wsr     = (const float*)d_in[8];
    const float* bsr     = (const float*)d_in[9];
    const float* conv_w  = (const float*)d_in[10];
    const float* conv_b  = (const float*)d_in[11];
    const float* fc_w    = (const float*)d_in[12];
    const float* fc_b    = (const float*)d_in[13];
    const float* cl0     = (const float*)d_in[14];
    const float* cr0     = (const float*)d_in[15];
    float* out = (float*)d_out;

    char* ws = (char*)d_ws;
    const size_t SZ = (size_t)SS * BB * DD * sizeof(float);  // 33.55 MB
    float* pre_l  = (float*)(ws);
    float* pre_r  = (float*)(ws + SZ);
    float* leftb  = (float*)(ws + 2 * SZ);
    float* rightb = (float*)(ws + 3 * SZ);
    float* pooled = (float*)(ws + 4 * SZ);

    pre_gemm_kernel<<<SS * (DD / 64), 256, 0, stream>>>(
        x, embed_w, Wsl, bsl, Wsr, bsr, pre_l, pre_r);

    recur_kernel<<<128, 1024, 0, stream>>>(
        Wl, bl, Wr, br, cl0, cr0, pre_l, pre_r, leftb, rightb);

    conv_pool_kernel<<<BB * (HH / 128), 256, 0, stream>>>(
        x, embed_w, leftb, rightb, conv_w, conv_b, pooled);

    fc_kernel<<<1, BB * NCLS, 0, stream>>>(pooled, fc_w, fc_b, out);
}

// Round 3
// 642.920 us; speedup vs baseline: 14.1099x; 2.7447x over previous
//
#include <hip/hip_runtime.h>
#include <hip/hip_bf16.h>

#define VOCAB 50000
#define DD 256
#define NCLS 10
#define BB 64
#define SS 512
#define HH 512
#define K3D 768

typedef __attribute__((ext_vector_type(8))) short bf16x8;
typedef __attribute__((ext_vector_type(8))) unsigned short ush8;
typedef __attribute__((ext_vector_type(4))) float f32x4;

static __device__ __forceinline__ unsigned short f2bf(float f) {
    __hip_bfloat16 h = __float2bfloat16(f);
    return *reinterpret_cast<unsigned short*>(&h);
}

// ---------------------------------------------------------------------------
// Kernel 0a: gather embedding rows -> bf16 e[b][s][d]
// ---------------------------------------------------------------------------
__global__ __launch_bounds__(256) void gather_e_kernel(
    const int* __restrict__ x, const float* __restrict__ embed_w,
    unsigned short* __restrict__ eb)
{
    const int g = blockIdx.x * 256 + threadIdx.x;  // chunk of 8 elements
    const int bs = g >> 5;                         // b*S + s
    const int d0 = (g & 31) * 8;
    const float* src = embed_w + (size_t)x[bs] * DD + d0;
    const float4 v0 = *(const float4*)(src);
    const float4 v1 = *(const float4*)(src + 4);
    ush8 o;
    o[0] = f2bf(v0.x); o[1] = f2bf(v0.y); o[2] = f2bf(v0.z); o[3] = f2bf(v0.w);
    o[4] = f2bf(v1.x); o[5] = f2bf(v1.y); o[6] = f2bf(v1.z); o[7] = f2bf(v1.w);
    *(ush8*)(eb + (size_t)g * 8) = o;
}

// ---------------------------------------------------------------------------
// Kernel 0b: conv_w fp32 -> bf16
// ---------------------------------------------------------------------------
__global__ __launch_bounds__(256) void cvt_w_kernel(
    const float* __restrict__ conv_w, unsigned short* __restrict__ wb)
{
    const int g = blockIdx.x * 256 + threadIdx.x;  // chunk of 8
    const float* src = conv_w + (size_t)g * 8;
    const float4 v0 = *(const float4*)(src);
    const float4 v1 = *(const float4*)(src + 4);
    ush8 o;
    o[0] = f2bf(v0.x); o[1] = f2bf(v0.y); o[2] = f2bf(v0.z); o[3] = f2bf(v0.w);
    o[4] = f2bf(v1.x); o[5] = f2bf(v1.y); o[6] = f2bf(v1.z); o[7] = f2bf(v1.w);
    *(ush8*)(wb + (size_t)g * 8) = o;
}

// ---------------------------------------------------------------------------
// Kernel 1: pre-GEMM with fused embedding gather (fp32, unchanged).
// ---------------------------------------------------------------------------
__global__ __launch_bounds__(256) void pre_gemm_kernel(
    const int* __restrict__ x, const float* __restrict__ embed_w,
    const float* __restrict__ Wsl, const float* __restrict__ bsl,
    const float* __restrict__ Wsr, const float* __restrict__ bsr,
    float* __restrict__ pre_l, float* __restrict__ pre_r)
{
    __shared__ float As[64][65];   // [b][k]
    __shared__ float Bl[64][65];   // [n][k]
    __shared__ float Br[64][65];
    __shared__ int   xs[64];

    const int s  = blockIdx.x >> 2;
    const int n0 = (blockIdx.x & 3) * 64;
    const int tid = threadIdx.x;
    const int bi = tid >> 4;
    const int ni = tid & 15;

    if (tid < 64) xs[tid] = x[tid * SS + s];

    float accl[4][4], accr[4][4];
#pragma unroll
    for (int r = 0; r < 4; ++r)
#pragma unroll
        for (int j = 0; j < 4; ++j) { accl[r][j] = 0.f; accr[r][j] = 0.f; }

    __syncthreads();

    for (int k0 = 0; k0 < DD; k0 += 64) {
#pragma unroll
        for (int j = 0; j < 16; ++j) {
            const int lin = tid + 256 * j;
            const int row = lin >> 6, col = lin & 63;
            As[row][col] = embed_w[(size_t)xs[row] * DD + k0 + col];
            Bl[row][col] = Wsl[(size_t)(n0 + row) * DD + k0 + col];
            Br[row][col] = Wsr[(size_t)(n0 + row) * DD + k0 + col];
        }
        __syncthreads();
#pragma unroll 8
        for (int k = 0; k < 64; ++k) {
            float a[4];
#pragma unroll
            for (int r = 0; r < 4; ++r) a[r] = As[bi * 4 + r][k];
#pragma unroll
            for (int j = 0; j < 4; ++j) {
                const float bvl = Bl[ni + 16 * j][k];
                const float bvr = Br[ni + 16 * j][k];
#pragma unroll
                for (int r = 0; r < 4; ++r) {
                    accl[r][j] += a[r] * bvl;
                    accr[r][j] += a[r] * bvr;
                }
            }
        }
        __syncthreads();
    }

#pragma unroll
    for (int r = 0; r < 4; ++r) {
        const int b = bi * 4 + r;
#pragma unroll
        for (int j = 0; j < 4; ++j) {
            const int n = n0 + ni + 16 * j;
            const size_t idx = ((size_t)s * BB + b) * DD + n;
            pre_l[idx] = accl[r][j] + bsl[n];
            pre_r[idx] = accr[r][j] + bsr[n];
        }
    }
}

// ---------------------------------------------------------------------------
// Kernel 2: the two recurrences (unchanged except bf16 output stores).
// ---------------------------------------------------------------------------
__global__ __launch_bounds__(1024) void recur_kernel(
    const float* __restrict__ Wl, const float* __restrict__ bl,
    const float* __restrict__ Wr, const float* __restrict__ br,
    const float* __restrict__ cl0, const float* __restrict__ cr0,
    const float* __restrict__ pre_l, const float* __restrict__ pre_r,
    unsigned short* __restrict__ outl, unsigned short* __restrict__ outr)
{
    __shared__ alignas(16) float cbuf[2][256];
    __shared__ float pbuf[2][256];

    const int bid = blockIdx.x;
    const int dir = bid >> 6;
    const int b   = bid & 63;
    const float* W    = dir ? Wr  : Wl;
    const float* bias = dir ? br  : bl;
    const float* c0   = dir ? cr0 : cl0;
    const float* pre  = dir ? pre_r : pre_l;
    unsigned short* out = dir ? outr : outl;

    const int tid = threadIdx.x;
    const int e = tid >> 2;
    const int q = tid & 3;

    // weights, pre-rotated so in-loop register index is STATIC
    float4 wreg[16];
    {
        const float4* wrow = (const float4*)(W + (size_t)e * DD + q * 64);
#pragma unroll
        for (int i = 0; i < 16; ++i) wreg[i] = wrow[(i + 2 * q) & 15];
    }
    const float blv = bias[e];

    if (tid < 256) {
        cbuf[0][tid] = c0[b * DD + tid];
        const int t0 = dir ? 511 : 0;
        pbuf[0][tid] = pre[((size_t)t0 * BB + b) * DD + tid];
    }
    float preg = 0.f;
    if (tid < 256) {
        const int t1 = dir ? 510 : 1;
        preg = pre[((size_t)t1 * BB + b) * DD + tid];
    }
    __syncthreads();

    int cur = 0;
    for (int k = 0; k < SS; ++k) {
        const int t = dir ? (SS - 1 - k) : k;

        float pnext = 0.f;
        if (tid < 256 && (k + 2) < SS) {
            const int t2 = dir ? (SS - 1 - (k + 2)) : (k + 2);
            pnext = pre[((size_t)t2 * BB + b) * DD + tid];
        }
        if (tid < 256) out[((size_t)b * SS + t) * DD + tid] = f2bf(cbuf[cur][tid]);

        if (k < SS - 1) {
            float partial = 0.f;
            const float4* c4 = (const float4*)cbuf[cur] + 16 * q;
#pragma unroll
            for (int ii = 0; ii < 16; ++ii) {
                const float4 cv = c4[(ii + 2 * q) & 15];  // runtime LDS addr: OK
                const float4 wv = wreg[ii];               // static reg index
                partial += wv.x * cv.x + wv.y * cv.y + wv.z * cv.z + wv.w * cv.w;
            }
            partial += __shfl_xor(partial, 1);
            partial += __shfl_xor(partial, 2);
            float v = partial + blv + pbuf[cur][e];
            v = v > 0.f ? v : 0.f;
            if (q == 0) cbuf[cur ^ 1][e] = v;
        }
        if (tid < 256 && (k + 1) < SS) pbuf[cur ^ 1][tid] = preg;
        preg = pnext;
        cur ^= 1;
        __syncthreads();
    }
}

// ---------------------------------------------------------------------------
// Kernel 3: conv(1x3D) + relu + maxpool, bf16 MFMA version.
// grid = B * (H/128) = 256 blocks, 256 threads (4 waves).
// Block: b fixed, h-tile 128. s-loop: 4 tiles of 128 rows. K = 768, 12
// double-buffered K-steps of 64. Wave w owns s-rows [32w,32w+32) x 128 h.
// pooled[b,h] = relu(max_s(acc) + conv_b[h])  (bias/relu deferred past max).
// LDS rows padded to 72 bf16 (144 B): rows hit banks 4r mod 32 -> 2-way only.
// ---------------------------------------------------------------------------
#define KSTEP 64
#define NK 12
#define NST 4
#define APAD 72

__global__ __launch_bounds__(256) void conv_pool_kernel(
    const unsigned short* __restrict__ leftb,
    const unsigned short* __restrict__ eb,
    const unsigned short* __restrict__ rightb,
    const unsigned short* __restrict__ convwb,
    const float* __restrict__ conv_b,
    float* __restrict__ pooled)
{
    __shared__ unsigned short Abuf[2][128][APAD];
    __shared__ unsigned short Bbuf[2][128][APAD];
    __shared__ float red[4][128];

    const int b   = blockIdx.x >> 2;
    const int h0  = (blockIdx.x & 3) * 128;
    const int tid = threadIdx.x;
    const int wid = tid >> 6;
    const int lane = tid & 63;
    const int lr  = lane & 15;        // fragment row/col index
    const int lk  = (lane >> 4) * 8;  // fragment k base

    f32x4 acc[2][8];
    float pmax[8];
#pragma unroll
    for (int ht = 0; ht < 8; ++ht) {
        pmax[ht] = -INFINITY;
        acc[0][ht] = (f32x4)(0.f);
        acc[1][ht] = (f32x4)(0.f);
    }

    const int strow = tid >> 3;   // staging row base (0..31)
    const int skc   = (tid & 7) * 8;

    // stage A(ctx slice, bf16 sources) + B(conv_w slice) for step `it`
    auto stage = [&](int it, int buf) {
        const int stile = it / NK, kstep = it % NK;
        const int k0 = kstep * KSTEP;
        const unsigned short* asrc = (k0 < DD) ? leftb : (k0 < 2 * DD ? eb : rightb);
        const int koff = k0 & (DD - 1);
        const int s0 = stile * 128;
#pragma unroll
        for (int j = 0; j < 4; ++j) {
            const int row = strow + 32 * j;
            const bf16x8 av = *(const bf16x8*)(asrc +
                ((size_t)(b * SS + s0 + row)) * DD + koff + skc);
            *(bf16x8*)&Abuf[buf][row][skc] = av;
            const bf16x8 bv = *(const bf16x8*)(convwb +
                (size_t)(h0 + row) * K3D + k0 + skc);
            *(bf16x8*)&Bbuf[buf][row][skc] = bv;
        }
    };

    stage(0, 0);
    int cur = 0;
    for (int it = 0; it < NST * NK; ++it) {
        __syncthreads();
        if (it + 1 < NST * NK) stage(it + 1, cur ^ 1);

        const int wrow0 = wid * 32;
#pragma unroll
        for (int ks = 0; ks < 2; ++ks) {
            const int kk = ks * 32 + lk;
            const bf16x8 a0 = *(const bf16x8*)&Abuf[cur][wrow0 + lr][kk];
            const bf16x8 a1 = *(const bf16x8*)&Abuf[cur][wrow0 + 16 + lr][kk];
#pragma unroll
            for (int ht = 0; ht < 8; ++ht) {
                const bf16x8 bv = *(const bf16x8*)&Bbuf[cur][ht * 16 + lr][kk];
                acc[0][ht] = __builtin_amdgcn_mfma_f32_16x16x32_bf16(a0, bv, acc[0][ht], 0, 0, 0);
                acc[1][ht] = __builtin_amdgcn_mfma_f32_16x16x32_bf16(a1, bv, acc[1][ht], 0, 0, 0);
            }
        }
        if ((it % NK) == NK - 1) {   // K finished for this s-tile: fold max
#pragma unroll
            for (int st = 0; st < 2; ++st)
#pragma unroll
                for (int ht = 0; ht < 8; ++ht) {
#pragma unroll
                    for (int r = 0; r < 4; ++r)
                        pmax[ht] = fmaxf(pmax[ht], acc[st][ht][r]);
                    acc[st][ht] = (f32x4)(0.f);
                }
        }
        cur ^= 1;
    }

    // reduce over lane row-groups (rows live on lane>>4 and reg index)
#pragma unroll
    for (int ht = 0; ht < 8; ++ht) {
        float m = pmax[ht];
        m = fmaxf(m, __shfl_xor(m, 16));
        m = fmaxf(m, __shfl_xor(m, 32));
        if (lane < 16) red[wid][ht * 16 + lane] = m;
    }
    __syncthreads();
    if (tid < 128) {
        const float m = fmaxf(fmaxf(red[0][tid], red[1][tid]),
                              fmaxf(red[2][tid], red[3][tid]));
        pooled[(size_t)b * HH + h0 + tid] = fmaxf(m + conv_b[h0 + tid], 0.f);
    }
}

// ---------------------------------------------------------------------------
// Kernel 4: final FC (unchanged).
// ---------------------------------------------------------------------------
__global__ void fc_kernel(const float* __restrict__ pooled,
                          const float* __restrict__ fc_w,
                          const float* __restrict__ fc_b,
                          float* __restrict__ out)
{
    const int t = threadIdx.x;
    if (t >= BB * NCLS) return;
    const int b = t / NCLS, c = t % NCLS;
    float acc = fc_b[c];
    for (int h = 0; h < HH; ++h)
        acc += pooled[(size_t)b * HH + h] * fc_w[(size_t)c * HH + h];
    out[b * NCLS + c] = acc;
}

// ---------------------------------------------------------------------------
extern "C" void kernel_launch(void* const* d_in, const int* in_sizes, int n_in,
                              void* d_out, int out_size, void* d_ws, size_t ws_size,
                              hipStream_t stream)
{
    const int*   x       = (const int*)  d_in[0];
    const float* embed_w = (const float*)d_in[1];
    const float* Wl      = (const float*)d_in[2];
    const float* bl      = (const float*)d_in[3];
    const float* Wsl     = (const float*)d_in[4];
    const float* bsl     = (const float*)d_in[5];
    const float* Wr      = (const float*)d_in[6];
    const float* br      = (const float*)d_in[7];
    const float* Wsr     = (const float*)d_in[8];
    const float* bsr     = (const float*)d_in[9];
    const float* conv_w  = (const float*)d_in[10];
    const float* conv_b  = (const float*)d_in[11];
    const float* fc_w    = (const float*)d_in[12];
    const float* fc_b    = (const float*)d_in[13];
    const float* cl0     = (const float*)d_in[14];
    const float* cr0     = (const float*)d_in[15];
    float* out = (float*)d_out;

    char* ws = (char*)d_ws;
    const size_t SZf = (size_t)SS * BB * DD * sizeof(float);           // 33.55 MB
    const size_t SZh = (size_t)SS * BB * DD * sizeof(unsigned short);  // 16.78 MB
    float*          pre_l  = (float*)(ws);
    float*          pre_r  = (float*)(ws + SZf);
    unsigned short* leftb  = (unsigned short*)(ws + 2 * SZf);
    unsigned short* rightb = (unsigned short*)(ws + 2 * SZf + SZh);
    unsigned short* eb     = (unsigned short*)(ws + 2 * SZf + 2 * SZh);
    unsigned short* convwb = (unsigned short*)(ws + 2 * SZf + 3 * SZh);
    float*          pooled = (float*)(ws + 2 * SZf + 3 * SZh + (size_t)HH * K3D * 2);

    gather_e_kernel<<<(BB * SS * DD / 8) / 256, 256, 0, stream>>>(x, embed_w, eb);
    cvt_w_kernel<<<(HH * K3D / 8) / 256, 256, 0, stream>>>(conv_w, convwb);

    pre_gemm_kernel<<<SS * (DD / 64), 256, 0, stream>>>(
        x, embed_w, Wsl, bsl, Wsr, bsr, pre_l, pre_r);

    recur_kernel<<<128, 1024, 0, stream>>>(
        Wl, bl, Wr, br, cl0, cr0, pre_l, pre_r, leftb, rightb);

    conv_pool_kernel<<<BB * (HH / 128), 256, 0, stream>>>(
        leftb, eb, rightb, convwb, conv_b, pooled);

    fc_kernel<<<1, BB * NCLS, 0, stream>>>(pooled, fc_w, fc_b, out);
}

// Round 4
// 632.336 us; speedup vs baseline: 14.3461x; 1.0167x over previous
//
#include <hip/hip_runtime.h>
#include <hip/hip_bf16.h>

#define VOCAB 50000
#define DD 256
#define NCLS 10
#define BB 64
#define SS 512
#define HH 512
#define K3D 768

typedef __attribute__((ext_vector_type(8))) short bf16x8;
typedef __attribute__((ext_vector_type(8))) unsigned short ush8;
typedef __attribute__((ext_vector_type(4))) float f32x4;

static __device__ __forceinline__ unsigned short f2bf(float f) {
    __hip_bfloat16 h = __float2bfloat16(f);
    return *reinterpret_cast<unsigned short*>(&h);
}

// ---------------------------------------------------------------------------
// Kernel 0a: gather embedding rows -> bf16 e[b][s][d]
// ---------------------------------------------------------------------------
__global__ __launch_bounds__(256) void gather_e_kernel(
    const int* __restrict__ x, const float* __restrict__ embed_w,
    unsigned short* __restrict__ eb)
{
    const int g = blockIdx.x * 256 + threadIdx.x;  // chunk of 8 elements
    const int bs = g >> 5;                         // b*S + s
    const int d0 = (g & 31) * 8;
    const float* src = embed_w + (size_t)x[bs] * DD + d0;
    const float4 v0 = *(const float4*)(src);
    const float4 v1 = *(const float4*)(src + 4);
    ush8 o;
    o[0] = f2bf(v0.x); o[1] = f2bf(v0.y); o[2] = f2bf(v0.z); o[3] = f2bf(v0.w);
    o[4] = f2bf(v1.x); o[5] = f2bf(v1.y); o[6] = f2bf(v1.z); o[7] = f2bf(v1.w);
    *(ush8*)(eb + (size_t)g * 8) = o;
}

// ---------------------------------------------------------------------------
// Kernel 0b: conv_w fp32 -> bf16
// ---------------------------------------------------------------------------
__global__ __launch_bounds__(256) void cvt_w_kernel(
    const float* __restrict__ conv_w, unsigned short* __restrict__ wb)
{
    const int g = blockIdx.x * 256 + threadIdx.x;  // chunk of 8
    const float* src = conv_w + (size_t)g * 8;
    const float4 v0 = *(const float4*)(src);
    const float4 v1 = *(const float4*)(src + 4);
    ush8 o;
    o[0] = f2bf(v0.x); o[1] = f2bf(v0.y); o[2] = f2bf(v0.z); o[3] = f2bf(v0.w);
    o[4] = f2bf(v1.x); o[5] = f2bf(v1.y); o[6] = f2bf(v1.z); o[7] = f2bf(v1.w);
    *(ush8*)(wb + (size_t)g * 8) = o;
}

// ---------------------------------------------------------------------------
// Kernel 1: pre-GEMM with fused embedding gather (fp32 math).
// NEW output layout for the MFMA recurrence, with BOTH biases folded in:
// pre2[s][bg][slot], slot=(n>>4)*256 + (b_loc>>2)*64 + (n&15)*4 + (b&3),
// where bg=b>>4, b_loc=b&15. value = e@Wsl^T + bsl + bl (resp. r).
// ---------------------------------------------------------------------------
__global__ __launch_bounds__(256) void pre_gemm_kernel(
    const int* __restrict__ x, const float* __restrict__ embed_w,
    const float* __restrict__ Wsl, const float* __restrict__ bsl,
    const float* __restrict__ bl,
    const float* __restrict__ Wsr, const float* __restrict__ bsr,
    const float* __restrict__ br,
    float* __restrict__ pre2_l, float* __restrict__ pre2_r)
{
    __shared__ float As[64][65];   // [b][k]
    __shared__ float Bl[64][65];   // [n][k]
    __shared__ float Br[64][65];
    __shared__ int   xs[64];

    const int s  = blockIdx.x >> 2;
    const int n0 = (blockIdx.x & 3) * 64;
    const int tid = threadIdx.x;
    const int bi = tid >> 4;
    const int ni = tid & 15;

    if (tid < 64) xs[tid] = x[tid * SS + s];

    float accl[4][4], accr[4][4];
#pragma unroll
    for (int r = 0; r < 4; ++r)
#pragma unroll
        for (int j = 0; j < 4; ++j) { accl[r][j] = 0.f; accr[r][j] = 0.f; }

    __syncthreads();

    for (int k0 = 0; k0 < DD; k0 += 64) {
#pragma unroll
        for (int j = 0; j < 16; ++j) {
            const int lin = tid + 256 * j;
            const int row = lin >> 6, col = lin & 63;
            As[row][col] = embed_w[(size_t)xs[row] * DD + k0 + col];
            Bl[row][col] = Wsl[(size_t)(n0 + row) * DD + k0 + col];
            Br[row][col] = Wsr[(size_t)(n0 + row) * DD + k0 + col];
        }
        __syncthreads();
#pragma unroll 8
        for (int k = 0; k < 64; ++k) {
            float a[4];
#pragma unroll
            for (int r = 0; r < 4; ++r) a[r] = As[bi * 4 + r][k];
#pragma unroll
            for (int j = 0; j < 4; ++j) {
                const float bvl = Bl[ni + 16 * j][k];
                const float bvr = Br[ni + 16 * j][k];
#pragma unroll
                for (int r = 0; r < 4; ++r) {
                    accl[r][j] += a[r] * bvl;
                    accr[r][j] += a[r] * bvr;
                }
            }
        }
        __syncthreads();
    }

#pragma unroll
    for (int r = 0; r < 4; ++r) {
        const int b = bi * 4 + r;
#pragma unroll
        for (int j = 0; j < 4; ++j) {
            const int n = n0 + ni + 16 * j;
            const size_t idx = ((size_t)s * 4 + (b >> 4)) * 4096
                             + (n >> 4) * 256 + ((b >> 2) & 3) * 64
                             + (n & 15) * 4 + (b & 3);
            pre2_l[idx] = accl[r][j] + bsl[n] + bl[n];
            pre2_r[idx] = accr[r][j] + bsr[n] + br[n];
        }
    }
}

// ---------------------------------------------------------------------------
// Kernel 2: MFMA recurrence. grid = 8 blocks (dir*4 + batch-group of 16),
// 256 threads (4 waves, wave w owns output features [64w, 64w+64)).
// Per step: c_new[16 b][256 e] = relu( c[16,256] @ W^T + pre2[t] ).
// W stationary in B-fragments (128 VGPR/lane, loaded once). State c in a
// double-buffered XOR-swizzled bf16 LDS tile. pre prefetched to registers.
// ---------------------------------------------------------------------------
#define CSWZ(row, off) ((off) ^ (((row) & 15) << 4))

__global__ __launch_bounds__(256, 1) void recur_mfma_kernel(
    const float* __restrict__ Wl, const float* __restrict__ Wr,
    const float* __restrict__ cl0, const float* __restrict__ cr0,
    const float* __restrict__ pre2_l, const float* __restrict__ pre2_r,
    unsigned short* __restrict__ outl, unsigned short* __restrict__ outr)
{
    __shared__ unsigned short cbf[2][16 * 256];  // [buf][b][e], swizzled rows

    const int dir = blockIdx.x >> 2;
    const int bg  = blockIdx.x & 3;
    const int b0  = bg * 16;
    const float* W   = dir ? Wr  : Wl;
    const float* c0  = dir ? cr0 : cl0;
    const float* pre = dir ? pre2_r : pre2_l;
    unsigned short* out = dir ? outr : outl;

    const int tid  = threadIdx.x;
    const int w    = tid >> 6;
    const int lane = tid & 63;
    const int col  = lane & 15;   // e-within-tile / batch row (A-read)
    const int g    = lane >> 4;   // k-group / batch-quad

    // --- stationary B-fragments: B[k][e] = W[e][k];
    // frag (nt,ks): e = w*64+nt*16+col, k = ks*32 + g*8 + j
    bf16x8 bfrag[4][8];
#pragma unroll
    for (int nt = 0; nt < 4; ++nt)
#pragma unroll
        for (int ks = 0; ks < 8; ++ks) {
            const float* src = W + (size_t)(w * 64 + nt * 16 + col) * DD
                                 + ks * 32 + g * 8;
            const float4 lo = *(const float4*)(src);
            const float4 hi = *(const float4*)(src + 4);
            ush8 p;
            p[0] = f2bf(lo.x); p[1] = f2bf(lo.y); p[2] = f2bf(lo.z); p[3] = f2bf(lo.w);
            p[4] = f2bf(hi.x); p[5] = f2bf(hi.y); p[6] = f2bf(hi.z); p[7] = f2bf(hi.w);
            bfrag[nt][ks] = *(bf16x8*)&p;
        }

    // --- init: cbf[0] = bf16(c0), out[:, t0] = bf16(c0)
    {
        const int blc = tid >> 4;     // 0..15 batch row
        const int ch  = tid & 15;     // 16-element chunk
        const float* src = c0 + (size_t)(b0 + blc) * DD + ch * 16;
        const float4 v0 = *(const float4*)(src);
        const float4 v1 = *(const float4*)(src + 4);
        const float4 v2 = *(const float4*)(src + 8);
        const float4 v3 = *(const float4*)(src + 12);
        ush8 p0, p1;
        p0[0]=f2bf(v0.x); p0[1]=f2bf(v0.y); p0[2]=f2bf(v0.z); p0[3]=f2bf(v0.w);
        p0[4]=f2bf(v1.x); p0[5]=f2bf(v1.y); p0[6]=f2bf(v1.z); p0[7]=f2bf(v1.w);
        p1[0]=f2bf(v2.x); p1[1]=f2bf(v2.y); p1[2]=f2bf(v2.z); p1[3]=f2bf(v2.w);
        p1[4]=f2bf(v3.x); p1[5]=f2bf(v3.y); p1[6]=f2bf(v3.z); p1[7]=f2bf(v3.w);
        char* rowp = (char*)cbf[0] + blc * 512;
        *(ush8*)(rowp + CSWZ(blc, ch * 32))      = p0;
        *(ush8*)(rowp + CSWZ(blc, ch * 32 + 16)) = p1;
        const int t0 = dir ? 511 : 0;
        ush8* dst = (ush8*)(out + ((size_t)(b0 + blc) * SS + t0) * DD + ch * 16);
        dst[0] = p0; dst[1] = p1;
    }

    // --- pre prefetch (registers, named ping-pong; slot layout matches lanes)
    const int pslot = (w * 4) * 256 + g * 64 + col * 4;  // + nt*256
    const float* pt0 = pre + ((size_t)(dir ? 511 : 0) * 4 + bg) * 4096;
    float4 pc0 = *(const float4*)(pt0 + pslot);
    float4 pc1 = *(const float4*)(pt0 + pslot + 256);
    float4 pc2 = *(const float4*)(pt0 + pslot + 512);
    float4 pc3 = *(const float4*)(pt0 + pslot + 768);

    __syncthreads();

    int cur = 0;
    for (int k = 0; k < SS - 1; ++k) {
        const int tdst  = dir ? (SS - 2 - k) : (k + 1);
        const int tnext = dir ? (SS - 2 - k) : (k + 1);   // pre source for k+1

        // A-fragments from cbf[cur]: row = col(lane&15), k = ks*32 + g*8
        bf16x8 afrag[8];
        {
            const char* rowp = (const char*)cbf[cur] + col * 512;
#pragma unroll
            for (int ks = 0; ks < 8; ++ks)
                afrag[ks] = *(const bf16x8*)(rowp + CSWZ(col, ks * 64 + g * 16));
        }

        // prefetch pre for next step
        float4 pn0, pn1, pn2, pn3;
        {
            const float* ptn = pre + ((size_t)tnext * 4 + bg) * 4096;
            pn0 = *(const float4*)(ptn + pslot);
            pn1 = *(const float4*)(ptn + pslot + 256);
            pn2 = *(const float4*)(ptn + pslot + 512);
            pn3 = *(const float4*)(ptn + pslot + 768);
        }

        // MFMA: acc[nt] over 8 k-steps
        f32x4 acc[4];
#pragma unroll
        for (int nt = 0; nt < 4; ++nt) acc[nt] = (f32x4)(0.f);
#pragma unroll
        for (int ks = 0; ks < 8; ++ks) {
            acc[0] = __builtin_amdgcn_mfma_f32_16x16x32_bf16(afrag[ks], bfrag[0][ks], acc[0], 0, 0, 0);
            acc[1] = __builtin_amdgcn_mfma_f32_16x16x32_bf16(afrag[ks], bfrag[1][ks], acc[1], 0, 0, 0);
            acc[2] = __builtin_amdgcn_mfma_f32_16x16x32_bf16(afrag[ks], bfrag[2][ks], acc[2], 0, 0, 0);
            acc[3] = __builtin_amdgcn_mfma_f32_16x16x32_bf16(afrag[ks], bfrag[3][ks], acc[3], 0, 0, 0);
        }

        // epilogue: v = relu(acc + pre); write to cbf[cur^1] (b16 scatter).
        // D layout: col = lane&15 (e), row = g*4 + r (batch).
        {
            char* nbuf = (char*)cbf[cur ^ 1];
#pragma unroll
            for (int nt = 0; nt < 4; ++nt) {
                const float4 pv = (nt == 0) ? pc0 : (nt == 1) ? pc1 : (nt == 2) ? pc2 : pc3;
                const int e2 = (w * 64 + nt * 16 + col) * 2;
#pragma unroll
                for (int r = 0; r < 4; ++r) {
                    const float pvr = (r == 0) ? pv.x : (r == 1) ? pv.y : (r == 2) ? pv.z : pv.w;
                    const float v = fmaxf(acc[nt][r] + pvr, 0.f);
                    const int rowb = g * 4 + r;
                    *(unsigned short*)(nbuf + rowb * 512 + CSWZ(rowb, e2)) = f2bf(v);
                }
            }
        }
        pc0 = pn0; pc1 = pn1; pc2 = pn2; pc3 = pn3;

        __syncthreads();

        // coalesced out store via LDS roundtrip
        {
            const int blc = tid >> 4;
            const int ch  = tid & 15;
            const char* rowp = (const char*)cbf[cur ^ 1] + blc * 512;
            const ush8 p0 = *(const ush8*)(rowp + CSWZ(blc, ch * 32));
            const ush8 p1 = *(const ush8*)(rowp + CSWZ(blc, ch * 32 + 16));
            ush8* dst = (ush8*)(out + ((size_t)(b0 + blc) * SS + tdst) * DD + ch * 16);
            dst[0] = p0; dst[1] = p1;
        }
        cur ^= 1;
    }
}

// ---------------------------------------------------------------------------
// Kernel 3: conv(1x3D) + relu + maxpool, bf16 MFMA (unchanged).
// ---------------------------------------------------------------------------
#define KSTEP 64
#define NK 12
#define NST 4
#define APAD 72

__global__ __launch_bounds__(256) void conv_pool_kernel(
    const unsigned short* __restrict__ leftb,
    const unsigned short* __restrict__ eb,
    const unsigned short* __restrict__ rightb,
    const unsigned short* __restrict__ convwb,
    const float* __restrict__ conv_b,
    float* __restrict__ pooled)
{
    __shared__ unsigned short Abuf[2][128][APAD];
    __shared__ unsigned short Bbuf[2][128][APAD];
    __shared__ float red[4][128];

    const int b   = blockIdx.x >> 2;
    const int h0  = (blockIdx.x & 3) * 128;
    const int tid = threadIdx.x;
    const int wid = tid >> 6;
    const int lane = tid & 63;
    const int lr  = lane & 15;
    const int lk  = (lane >> 4) * 8;

    f32x4 acc[2][8];
    float pmax[8];
#pragma unroll
    for (int ht = 0; ht < 8; ++ht) {
        pmax[ht] = -INFINITY;
        acc[0][ht] = (f32x4)(0.f);
        acc[1][ht] = (f32x4)(0.f);
    }

    const int strow = tid >> 3;
    const int skc   = (tid & 7) * 8;

    auto stage = [&](int it, int buf) {
        const int stile = it / NK, kstep = it % NK;
        const int k0 = kstep * KSTEP;
        const unsigned short* asrc = (k0 < DD) ? leftb : (k0 < 2 * DD ? eb : rightb);
        const int koff = k0 & (DD - 1);
        const int s0 = stile * 128;
#pragma unroll
        for (int j = 0; j < 4; ++j) {
            const int row = strow + 32 * j;
            const bf16x8 av = *(const bf16x8*)(asrc +
                ((size_t)(b * SS + s0 + row)) * DD + koff + skc);
            *(bf16x8*)&Abuf[buf][row][skc] = av;
            const bf16x8 bv = *(const bf16x8*)(convwb +
                (size_t)(h0 + row) * K3D + k0 + skc);
            *(bf16x8*)&Bbuf[buf][row][skc] = bv;
        }
    };

    stage(0, 0);
    int cur = 0;
    for (int it = 0; it < NST * NK; ++it) {
        __syncthreads();
        if (it + 1 < NST * NK) stage(it + 1, cur ^ 1);

        const int wrow0 = wid * 32;
#pragma unroll
        for (int ks = 0; ks < 2; ++ks) {
            const int kk = ks * 32 + lk;
            const bf16x8 a0 = *(const bf16x8*)&Abuf[cur][wrow0 + lr][kk];
            const bf16x8 a1 = *(const bf16x8*)&Abuf[cur][wrow0 + 16 + lr][kk];
#pragma unroll
            for (int ht = 0; ht < 8; ++ht) {
                const bf16x8 bv = *(const bf16x8*)&Bbuf[cur][ht * 16 + lr][kk];
                acc[0][ht] = __builtin_amdgcn_mfma_f32_16x16x32_bf16(a0, bv, acc[0][ht], 0, 0, 0);
                acc[1][ht] = __builtin_amdgcn_mfma_f32_16x16x32_bf16(a1, bv, acc[1][ht], 0, 0, 0);
            }
        }
        if ((it % NK) == NK - 1) {
#pragma unroll
            for (int st = 0; st < 2; ++st)
#pragma unroll
                for (int ht = 0; ht < 8; ++ht) {
#pragma unroll
                    for (int r = 0; r < 4; ++r)
                        pmax[ht] = fmaxf(pmax[ht], acc[st][ht][r]);
                    acc[st][ht] = (f32x4)(0.f);
                }
        }
        cur ^= 1;
    }

#pragma unroll
    for (int ht = 0; ht < 8; ++ht) {
        float m = pmax[ht];
        m = fmaxf(m, __shfl_xor(m, 16));
        m = fmaxf(m, __shfl_xor(m, 32));
        if (lane < 16) red[wid][ht * 16 + lane] = m;
    }
    __syncthreads();
    if (tid < 128) {
        const float m = fmaxf(fmaxf(red[0][tid], red[1][tid]),
                              fmaxf(red[2][tid], red[3][tid]));
        pooled[(size_t)b * HH + h0 + tid] = fmaxf(m + conv_b[h0 + tid], 0.f);
    }
}

// ---------------------------------------------------------------------------
// Kernel 4: final FC (unchanged).
// ---------------------------------------------------------------------------
__global__ void fc_kernel(const float* __restrict__ pooled,
                          const float* __restrict__ fc_w,
                          const float* __restrict__ fc_b,
                          float* __restrict__ out)
{
    const int t = threadIdx.x;
    if (t >= BB * NCLS) return;
    const int b = t / NCLS, c = t % NCLS;
    float acc = fc_b[c];
    for (int h = 0; h < HH; ++h)
        acc += pooled[(size_t)b * HH + h] * fc_w[(size_t)c * HH + h];
    out[b * NCLS + c] = acc;
}

// ---------------------------------------------------------------------------
extern "C" void kernel_launch(void* const* d_in, const int* in_sizes, int n_in,
                              void* d_out, int out_size, void* d_ws, size_t ws_size,
                              hipStream_t stream)
{
    const int*   x       = (const int*)  d_in[0];
    const float* embed_w = (const float*)d_in[1];
    const float* Wl      = (const float*)d_in[2];
    const float* bl      = (const float*)d_in[3];
    const float* Wsl     = (const float*)d_in[4];
    const float* bsl     = (const float*)d_in[5];
    const float* Wr      = (const float*)d_in[6];
    const float* br      = (const float*)d_in[7];
    const float* Wsr     = (const float*)d_in[8];
    const float* bsr     = (const float*)d_in[9];
    const float* conv_w  = (const float*)d_in[10];
    const float* conv_b  = (const float*)d_in[11];
    const float* fc_w    = (const float*)d_in[12];
    const float* fc_b    = (const float*)d_in[13];
    const float* cl0     = (const float*)d_in[14];
    const float* cr0     = (const float*)d_in[15];
    float* out = (float*)d_out;

    char* ws = (char*)d_ws;
    const size_t SZf = (size_t)SS * BB * DD * sizeof(float);           // 33.55 MB
    const size_t SZh = (size_t)SS * BB * DD * sizeof(unsigned short);  // 16.78 MB
    float*          pre2_l = (float*)(ws);
    float*          pre2_r = (float*)(ws + SZf);
    unsigned short* leftb  = (unsigned short*)(ws + 2 * SZf);
    unsigned short* rightb = (unsigned short*)(ws + 2 * SZf + SZh);
    unsigned short* eb     = (unsigned short*)(ws + 2 * SZf + 2 * SZh);
    unsigned short* convwb = (unsigned short*)(ws + 2 * SZf + 3 * SZh);
    float*          pooled = (float*)(ws + 2 * SZf + 3 * SZh + (size_t)HH * K3D * 2);

    gather_e_kernel<<<(BB * SS * DD / 8) / 256, 256, 0, stream>>>(x, embed_w, eb);
    cvt_w_kernel<<<(HH * K3D / 8) / 256, 256, 0, stream>>>(conv_w, convwb);

    pre_gemm_kernel<<<SS * (DD / 64), 256, 0, stream>>>(
        x, embed_w, Wsl, bsl, bl, Wsr, bsr, br, pre2_l, pre2_r);

    recur_mfma_kernel<<<8, 256, 0, stream>>>(
        Wl, Wr, cl0, cr0, pre2_l, pre2_r, leftb, rightb);

    conv_pool_kernel<<<BB * (HH / 128), 256, 0, stream>>>(
        leftb, eb, rightb, convwb, conv_b, pooled);

    fc_kernel<<<1, BB * NCLS, 0, stream>>>(pooled, fc_w, fc_b, out);
}